// Round 2
// baseline (129.102 us; speedup 1.0000x reference)
//
#include <hip/hip_runtime.h>
#include <cstdint>

// Self-attention (q=k=v=x), B=4, S=4096, D=64, fp32 in/out.
// Round 2: precompute bf16 hi/lo split of x into d_ws (K-format row-major +
// V^T slot-permuted format), then a flash kernel whose K/V MFMA fragments are
// loaded straight from global into registers (no main-loop LDS, no per-block
// re-conversion). 256 blocks x 512 threads; each wave: 64 q x 512 kv span;
// LDS used only for the final 8-way partial merge.

#define SB 4096
#define DDIM 64

typedef __attribute__((ext_vector_type(16))) float f32x16;
typedef __attribute__((ext_vector_type(8)))  float f32x8;
typedef __attribute__((ext_vector_type(4)))  float f32x4;
typedef __attribute__((ext_vector_type(8)))  short bf16x8;

static __device__ __forceinline__ unsigned short bf16_rne(float f) {
  union { float f; uint32_t u; } v; v.f = f;
  uint32_t u = v.u + 0x7FFFu + ((v.u >> 16) & 1u);
  return (unsigned short)(u >> 16);
}
static __device__ __forceinline__ float bf16_tof(unsigned short h) {
  union { uint32_t u; float f; } v; v.u = ((uint32_t)h) << 16;
  return v.f;
}
static __device__ __forceinline__ f32x16 MFMA(bf16x8 a, bf16x8 b, f32x16 c) {
  return __builtin_amdgcn_mfma_f32_32x32x16_bf16(a, b, c, 0, 0, 0);
}

// ---- workspace layout ----
// kfmt: [b*4096+row] * 256 B : 64 hi bf16 | 64 lo bf16          (4 MB)
// vthi: [(b*64+d)] * 8192 B  : 4096 slot-permuted hi bf16       (2 MB)
// vtlo: same layout, lo                                          (2 MB)
#define KF_BYTES  (4u << 20)
#define VT_BYTES  (2u << 20)
#define WS_NEEDED (8u << 20)

// slot s (0..15) within a 16-chunk holds k-offset koff[s]:
// koff = 4*rev2(s>>2) + (s&3), rev2: 0,2,1,3
__device__ __constant__ int g_koff[16] = {0,1,2,3, 8,9,10,11, 4,5,6,7, 12,13,14,15};

// ================= precompute kernel =================
__global__ __launch_bounds__(256)
void precompute_kernel(const float* __restrict__ x, char* __restrict__ ws) {
  const int bid = blockIdx.x;
  const int tid = threadIdx.x;
  char* __restrict__ kfmt = ws;
  char* __restrict__ vthi = ws + KF_BYTES;
  char* __restrict__ vtlo = ws + KF_BYTES + VT_BYTES;
  if (bid < 512) {
    // K-format: thread -> (row, seg of 8 elems)
    const int t   = bid * 256 + tid;      // 0..131071
    const int row = t >> 3;               // 0..16383
    const int seg = t & 7;
    f32x8 v = *(const f32x8*)(x + (size_t)row * 64 + seg * 8);
    bf16x8 h, l;
#pragma unroll
    for (int j = 0; j < 8; ++j) {
      unsigned short hi = bf16_rne(v[j]);
      h[j] = (short)hi;
      l[j] = (short)bf16_rne(v[j] - bf16_tof(hi));
    }
    char* dst = kfmt + (size_t)row * 256 + seg * 16;
    *(bf16x8*)dst         = h;
    *(bf16x8*)(dst + 128) = l;
  } else {
    // V^T slot-permuted: wave -> (b, chunk c); lane = d
    const int w = (bid - 512) * 4 + (tid >> 6); // 0..1023
    const int b = w >> 8;
    const int c = w & 255;
    const int d = tid & 63;
    unsigned short hs[16], ls[16];
#pragma unroll
    for (int s = 0; s < 16; ++s) {
      const int k = c * 16 + g_koff[s];
      float v = x[((size_t)(b * SB + k)) * 64 + d];
      hs[s] = bf16_rne(v);
      ls[s] = bf16_rne(v - bf16_tof(hs[s]));
    }
    bf16x8 h0, h1, l0, l1;
#pragma unroll
    for (int j = 0; j < 8; ++j) {
      h0[j] = (short)hs[j];     h1[j] = (short)hs[j + 8];
      l0[j] = (short)ls[j];     l1[j] = (short)ls[j + 8];
    }
    char* dh = vthi + (size_t)(b * 64 + d) * 8192 + c * 32;
    char* dl = vtlo + (size_t)(b * 64 + d) * 8192 + c * 32;
    *(bf16x8*)dh = h0; *(bf16x8*)(dh + 16) = h1;
    *(bf16x8*)dl = l0; *(bf16x8*)(dl + 16) = l1;
  }
}

// ================= main kernel =================
__global__ __launch_bounds__(512, 2)
void sdpa_main(const float* __restrict__ x, const char* __restrict__ ws,
               float* __restrict__ out) {
  __shared__ __align__(16) char smem[121856];   // merge only: 7 * 17408
  const int tid  = threadIdx.x;
  const int wv   = tid >> 6;
  const int lane = tid & 63;
  const int l31  = lane & 31;
  const int h5   = lane >> 5;

  // XCD-swizzle: XCD x handles batch x>>1 -> per-XCD working set ~2MB (L2-fit)
  const int p    = blockIdx.x;
  const int xcd  = p & 7;
  const int slot = p >> 3;
  const int b    = xcd >> 1;
  const int q0   = ((xcd & 1) * 32 + slot) * 64;

  const float* __restrict__ xb = x + (size_t)b * (SB * DDIM);
  const char* __restrict__ kfmt = ws;
  const char* __restrict__ vthi = ws + KF_BYTES;
  const char* __restrict__ vtlo = ws + KF_BYTES + VT_BYTES;

  const float NEG = -3.0e38f;

  // ---- Q fragments from x (fp32), scaled by 0.125, split hi/lo ----
  bf16x8 qh[2][4], ql[2][4];
#pragma unroll
  for (int qf = 0; qf < 2; ++qf) {
#pragma unroll
    for (int dc = 0; dc < 4; ++dc) {
      const float* ptr = xb + (size_t)(q0 + qf * 32 + l31) * DDIM + dc * 16 + h5 * 8;
      f32x4 a = *(const f32x4*)ptr;
      f32x4 c = *(const f32x4*)(ptr + 4);
      float v[8] = {a[0], a[1], a[2], a[3], c[0], c[1], c[2], c[3]};
#pragma unroll
      for (int j = 0; j < 8; ++j) {
        float sv = v[j] * 0.125f;
        unsigned short hi = bf16_rne(sv);
        qh[qf][dc][j] = (short)hi;
        ql[qf][dc][j] = (short)bf16_rne(sv - bf16_tof(hi));
      }
    }
  }

  f32x16 ot[2][2] = {};
  float mrun[2] = {NEG, NEG};
  float lrun[2] = {0.f, 0.f};

  const int kv0 = wv * (SB / 8);   // private 512-row KV span

  // byte pointers for fragment loads
  const char* kbase = kfmt + (size_t)(b * SB + kv0 + l31) * 256 + h5 * 16;
  const char* vbh   = vthi + (size_t)(b * 64 + l31) * 8192 + (size_t)kv0 * 2 + h5 * 16;
  const char* vbl   = vtlo + (size_t)(b * 64 + l31) * 8192 + (size_t)kv0 * 2 + h5 * 16;

#pragma unroll 1
  for (int st = 0; st < 16; ++st) {
    // ---- K fragments straight from global ----
    bf16x8 kh[4], kl[4];
#pragma unroll
    for (int dc = 0; dc < 4; ++dc) {
      kh[dc] = *(const bf16x8*)(kbase + dc * 32);
      kl[dc] = *(const bf16x8*)(kbase + 128 + dc * 32);
    }

    // ---- QK^T: S^T = mfma(K, Q) ----
    f32x16 s0 = {}, s1 = {};
#pragma unroll
    for (int dc = 0; dc < 4; ++dc) {
      s0 = MFMA(kh[dc], qh[0][dc], s0);
      s1 = MFMA(kh[dc], qh[1][dc], s1);
      s0 = MFMA(kh[dc], ql[0][dc], s0);
      s1 = MFMA(kh[dc], ql[1][dc], s1);
      s0 = MFMA(kl[dc], qh[0][dc], s0);
      s1 = MFMA(kl[dc], qh[1][dc], s1);
    }

    // ---- issue V fragment loads now; softmax hides their latency ----
    bf16x8 vh[2][2], vl[2][2];
#pragma unroll
    for (int df = 0; df < 2; ++df)
#pragma unroll
      for (int c = 0; c < 2; ++c) {
        vh[df][c] = *(const bf16x8*)(vbh + (size_t)df * (32 * 8192) + c * 32);
        vl[df][c] = *(const bf16x8*)(vbl + (size_t)df * (32 * 8192) + c * 32);
      }

    // ---- online softmax (lane owns q = l31 + 32*qf across k-slice) ----
    bf16x8 ph[2][2], pl[2][2];
#pragma unroll
    for (int qf = 0; qf < 2; ++qf) {
      f32x16 sv = qf ? s1 : s0;
      float pm = sv[0];
#pragma unroll
      for (int r = 1; r < 16; ++r) pm = fmaxf(pm, sv[r]);
      pm = fmaxf(pm, __shfl_xor(pm, 32));
      const float mnew = fmaxf(mrun[qf], pm);
      const float corr = __expf(mrun[qf] - mnew);
      mrun[qf] = mnew;
      lrun[qf] *= corr;
#pragma unroll
      for (int df = 0; df < 2; ++df)
#pragma unroll
        for (int r = 0; r < 16; ++r) ot[qf][df][r] *= corr;
      float pv[16]; float ps = 0.f;
#pragma unroll
      for (int r = 0; r < 16; ++r) { pv[r] = __expf(sv[r] - mnew); ps += pv[r]; }
      lrun[qf] += ps;
#pragma unroll
      for (int c = 0; c < 2; ++c)
#pragma unroll
        for (int j = 0; j < 8; ++j) {
          float pvv = pv[c * 8 + j];
          unsigned short hi = bf16_rne(pvv);
          ph[qf][c][j] = (short)hi;
          pl[qf][c][j] = (short)bf16_rne(pvv - bf16_tof(hi));
        }
    }

    // ---- PV: O^T += mfma(V^T, P^T) ----
#pragma unroll
    for (int df = 0; df < 2; ++df)
#pragma unroll
      for (int qf = 0; qf < 2; ++qf)
#pragma unroll
        for (int c = 0; c < 2; ++c) {
          ot[qf][df] = MFMA(vh[df][c], ph[qf][c], ot[qf][df]);
          ot[qf][df] = MFMA(vh[df][c], pl[qf][c], ot[qf][df]);
          ot[qf][df] = MFMA(vl[df][c], ph[qf][c], ot[qf][df]);
        }

    kbase += 32 * 256;
    vbh   += 64;
    vbl   += 64;
  }

#pragma unroll
  for (int qf = 0; qf < 2; ++qf) lrun[qf] += __shfl_xor(lrun[qf], 32);

  // ---- cross-wave merge (LDS), wave 0 finalizes ----
  __syncthreads();
  if (wv > 0) {
    char* rbase = smem + (size_t)(wv - 1) * 17408 + (size_t)lane * 272;
#pragma unroll
    for (int qf = 0; qf < 2; ++qf)
#pragma unroll
      for (int df = 0; df < 2; ++df)
#pragma unroll
        for (int t = 0; t < 4; ++t) {
          f32x4 o = { ot[qf][df][t*4+0], ot[qf][df][t*4+1],
                      ot[qf][df][t*4+2], ot[qf][df][t*4+3] };
          *(f32x4*)(rbase + (qf * 128 + df * 64 + t * 16)) = o;
        }
    f32x4 stv = { mrun[0], lrun[0], mrun[1], lrun[1] };
    *(f32x4*)(rbase + 256) = stv;
  }
  __syncthreads();
  if (wv == 0) {
#pragma unroll 1
    for (int w = 1; w < 8; ++w) {
      char* rbase = smem + (size_t)(w - 1) * 17408 + (size_t)lane * 272;
      f32x4 stv = *(f32x4*)(rbase + 256);
#pragma unroll
      for (int qf = 0; qf < 2; ++qf) {
        const float mw = stv[qf * 2 + 0];
        const float lw = stv[qf * 2 + 1];
        const float mn = fmaxf(mrun[qf], mw);
        const float f0 = __expf(mrun[qf] - mn);
        const float f1 = __expf(mw - mn);
        mrun[qf] = mn;
        lrun[qf] = lrun[qf] * f0 + lw * f1;
#pragma unroll
        for (int df = 0; df < 2; ++df)
#pragma unroll
          for (int t = 0; t < 4; ++t) {
            f32x4 o = *(f32x4*)(rbase + (qf * 128 + df * 64 + t * 16));
#pragma unroll
            for (int e = 0; e < 4; ++e)
              ot[qf][df][t*4+e] = ot[qf][df][t*4+e] * f0 + o[e] * f1;
          }
      }
    }
#pragma unroll
    for (int qf = 0; qf < 2; ++qf) {
      const float inv = 1.0f / lrun[qf];
      const size_t rowoff = ((size_t)b * SB + q0 + qf * 32 + l31) * DDIM;
#pragma unroll
      for (int df = 0; df < 2; ++df)
#pragma unroll
        for (int t = 0; t < 4; ++t) {
          const int dbase = df * 32 + t * 8 + h5 * 4;
          f32x4 o = { ot[qf][df][t*4+0] * inv, ot[qf][df][t*4+1] * inv,
                      ot[qf][df][t*4+2] * inv, ot[qf][df][t*4+3] * inv };
          *(f32x4*)(out + rowoff + dbase) = o;
        }
    }
  }
}

// ================= fallback (verified round-1 kernel) =================
#define KSTRIDE 272
#define VSTRIDE 144
#define VOFF    8704
#define WREG    17920

__global__ __launch_bounds__(512, 1)
void sdpa_fb(const float* __restrict__ x, float* __restrict__ out) {
  __shared__ __align__(16) char smem[143360];
  const int tid  = threadIdx.x;
  const int wv   = tid >> 6;
  const int lane = tid & 63;
  const int l31  = lane & 31;
  const int h5   = lane >> 5;
  const int bid  = blockIdx.x;
  const int b    = bid >> 6;
  const int q0   = (bid & 63) << 6;
  const float* __restrict__ xb = x + (size_t)b * (SB * DDIM);
  char* __restrict__ wl = smem + (size_t)wv * WREG;
  const float NEG = -3.0e38f;

  bf16x8 qh[2][4], ql[2][4];
#pragma unroll
  for (int qf = 0; qf < 2; ++qf)
#pragma unroll
    for (int dc = 0; dc < 4; ++dc) {
      const float* ptr = xb + (size_t)(q0 + qf * 32 + l31) * DDIM + dc * 16 + h5 * 8;
      f32x4 a = *(const f32x4*)ptr;
      f32x4 c = *(const f32x4*)(ptr + 4);
      float v[8] = {a[0], a[1], a[2], a[3], c[0], c[1], c[2], c[3]};
#pragma unroll
      for (int j = 0; j < 8; ++j) {
        float sv = v[j] * 0.125f;
        unsigned short hi = bf16_rne(sv);
        qh[qf][dc][j] = (short)hi;
        ql[qf][dc][j] = (short)bf16_rne(sv - bf16_tof(hi));
      }
    }

  f32x16 ot[2][2] = {};
  float mrun[2] = {NEG, NEG};
  float lrun[2] = {0.f, 0.f};
  const int kv0 = wv * (SB / 8);
  const int r0  = (lane >> 3) * 4;
  const int d0g = (lane & 7) * 8;
  const int vc  = r0 >> 4;
  const int vko = r0 & 15;
  const int vsA = ((vko >> 2) & 1) * 8 + ((vko >> 3) & 1) * 4;
  const uint32_t vcolb = (uint32_t)(vc * 16 + vsA) * 2;

#pragma unroll 1
  for (int st = 0; st < 16; ++st) {
    const int krow0 = kv0 + st * 32;
    bf16x8 hv[4], lv[4];
#pragma unroll
    for (int i = 0; i < 4; ++i) {
      f32x8 t = *(const f32x8*)(xb + (size_t)(krow0 + r0 + i) * DDIM + d0g);
#pragma unroll
      for (int j = 0; j < 8; ++j) {
        unsigned short hi = bf16_rne(t[j]);
        hv[i][j] = (short)hi;
        lv[i][j] = (short)bf16_rne(t[j] - bf16_tof(hi));
      }
      const int row = r0 + i;
      *(bf16x8*)(wl + row * KSTRIDE + d0g * 2)       = hv[i];
      *(bf16x8*)(wl + row * KSTRIDE + 128 + d0g * 2) = lv[i];
    }
#pragma unroll
    for (int dd = 0; dd < 8; ++dd) {
      const int d = d0g + dd;
      const uint32_t sw = ((uint32_t)((d >> 3) & 7)) << 4;
      char* rb = wl + VOFF + (uint32_t)d * VSTRIDE;
      short4 pa = make_short4(hv[0][dd], hv[1][dd], hv[2][dd], hv[3][dd]);
      short4 pb = make_short4(lv[0][dd], lv[1][dd], lv[2][dd], lv[3][dd]);
      *(short4*)(rb + (vcolb ^ sw))        = pa;
      *(short4*)(rb + ((64 + vcolb) ^ sw)) = pb;
    }

    bf16x8 kh[4], kl[4];
    {
      char* krow = wl + l31 * KSTRIDE;
#pragma unroll
      for (int dc = 0; dc < 4; ++dc) {
        const uint32_t off = (uint32_t)(dc * 32 + h5 * 16);
        kh[dc] = *(bf16x8*)(krow + off);
        kl[dc] = *(bf16x8*)(krow + 128 + off);
      }
    }
    f32x16 s0 = {}, s1 = {};
#pragma unroll
    for (int dc = 0; dc < 4; ++dc) {
      s0 = MFMA(kh[dc], qh[0][dc], s0);
      s1 = MFMA(kh[dc], qh[1][dc], s1);
      s0 = MFMA(kh[dc], ql[0][dc], s0);
      s1 = MFMA(kh[dc], ql[1][dc], s1);
      s0 = MFMA(kl[dc], qh[0][dc], s0);
      s1 = MFMA(kl[dc], qh[1][dc], s1);
    }

    bf16x8 ph[2][2], pl[2][2];
#pragma unroll
    for (int qf = 0; qf < 2; ++qf) {
      f32x16 sv = qf ? s1 : s0;
      float pm = sv[0];
#pragma unroll
      for (int r = 1; r < 16; ++r) pm = fmaxf(pm, sv[r]);
      pm = fmaxf(pm, __shfl_xor(pm, 32));
      const float mnew = fmaxf(mrun[qf], pm);
      const float corr = __expf(mrun[qf] - mnew);
      mrun[qf] = mnew;
      lrun[qf] *= corr;
#pragma unroll
      for (int df = 0; df < 2; ++df)
#pragma unroll
        for (int r = 0; r < 16; ++r) ot[qf][df][r] *= corr;
      float pv[16]; float ps = 0.f;
#pragma unroll
      for (int r = 0; r < 16; ++r) { pv[r] = __expf(sv[r] - mnew); ps += pv[r]; }
      lrun[qf] += ps;
#pragma unroll
      for (int c = 0; c < 2; ++c)
#pragma unroll
        for (int j = 0; j < 8; ++j) {
          float pvv = pv[c * 8 + j];
          unsigned short hi = bf16_rne(pvv);
          ph[qf][c][j] = (short)hi;
          pl[qf][c][j] = (short)bf16_rne(pvv - bf16_tof(hi));
        }
    }

#pragma unroll
    for (int df = 0; df < 2; ++df) {
      const int d = df * 32 + l31;
      char* rb = wl + VOFF + (uint32_t)d * VSTRIDE;
      const uint32_t sw = ((uint32_t)((d >> 3) & 7)) << 4;
      bf16x8 vh[2], vl2[2];
#pragma unroll
      for (int c = 0; c < 2; ++c) {
        const uint32_t off = (uint32_t)(c * 32 + h5 * 16);
        vh[c]  = *(bf16x8*)(rb + (off ^ sw));
        vl2[c] = *(bf16x8*)(rb + ((64 + off) ^ sw));
      }
#pragma unroll
      for (int qf = 0; qf < 2; ++qf)
#pragma unroll
        for (int c = 0; c < 2; ++c) {
          ot[qf][df] = MFMA(vh[c],  ph[qf][c], ot[qf][df]);
          ot[qf][df] = MFMA(vh[c],  pl[qf][c], ot[qf][df]);
          ot[qf][df] = MFMA(vl2[c], ph[qf][c], ot[qf][df]);
        }
    }
  }

#pragma unroll
  for (int qf = 0; qf < 2; ++qf) lrun[qf] += __shfl_xor(lrun[qf], 32);

  __syncthreads();
  if (wv > 0) {
    char* rbase = smem + (size_t)(wv - 1) * 17408 + (size_t)lane * 272;
#pragma unroll
    for (int qf = 0; qf < 2; ++qf)
#pragma unroll
      for (int df = 0; df < 2; ++df)
#pragma unroll
        for (int t = 0; t < 4; ++t) {
          f32x4 o = { ot[qf][df][t*4+0], ot[qf][df][t*4+1],
                      ot[qf][df][t*4+2], ot[qf][df][t*4+3] };
          *(f32x4*)(rbase + (qf * 128 + df * 64 + t * 16)) = o;
        }
    f32x4 stv = { mrun[0], lrun[0], mrun[1], lrun[1] };
    *(f32x4*)(rbase + 256) = stv;
  }
  __syncthreads();
  if (wv == 0) {
#pragma unroll 1
    for (int w = 1; w < 8; ++w) {
      char* rbase = smem + (size_t)(w - 1) * 17408 + (size_t)lane * 272;
      f32x4 stv = *(f32x4*)(rbase + 256);
#pragma unroll
      for (int qf = 0; qf < 2; ++qf) {
        const float mw = stv[qf * 2 + 0];
        const float lw = stv[qf * 2 + 1];
        const float mn = fmaxf(mrun[qf], mw);
        const float f0 = __expf(mrun[qf] - mn);
        const float f1 = __expf(mw - mn);
        mrun[qf] = mn;
        lrun[qf] = lrun[qf] * f0 + lw * f1;
#pragma unroll
        for (int df = 0; df < 2; ++df)
#pragma unroll
          for (int t = 0; t < 4; ++t) {
            f32x4 o = *(f32x4*)(rbase + (qf * 128 + df * 64 + t * 16));
#pragma unroll
            for (int e = 0; e < 4; ++e)
              ot[qf][df][t*4+e] = ot[qf][df][t*4+e] * f0 + o[e] * f1;
          }
      }
    }
#pragma unroll
    for (int qf = 0; qf < 2; ++qf) {
      const float inv = 1.0f / lrun[qf];
      const size_t rowoff = ((size_t)b * SB + q0 + qf * 32 + l31) * DDIM;
#pragma unroll
      for (int df = 0; df < 2; ++df)
#pragma unroll
        for (int t = 0; t < 4; ++t) {
          const int dbase = df * 32 + t * 8 + h5 * 4;
          f32x4 o = { ot[qf][df][t*4+0] * inv, ot[qf][df][t*4+1] * inv,
                      ot[qf][df][t*4+2] * inv, ot[qf][df][t*4+3] * inv };
          *(f32x4*)(out + rowoff + dbase) = o;
        }
    }
  }
}

extern "C" void kernel_launch(void* const* d_in, const int* in_sizes, int n_in,
                              void* d_out, int out_size, void* d_ws, size_t ws_size,
                              hipStream_t stream) {
  (void)in_sizes; (void)n_in; (void)out_size;
  const float* x = (const float*)d_in[0];
  float* o = (float*)d_out;
  if (ws_size >= (size_t)WS_NEEDED) {
    precompute_kernel<<<dim3(768), dim3(256), 0, stream>>>(x, (char*)d_ws);
    sdpa_main<<<dim3(256), dim3(512), 0, stream>>>(x, (const char*)d_ws, o);
  } else {
    sdpa_fb<<<dim3(256), dim3(512), 0, stream>>>(x, o);
  }
}